// Round 9
// baseline (637.933 us; speedup 1.0000x reference)
//
#include <hip/hip_runtime.h>
#include <math.h>

typedef unsigned short u16;
typedef __attribute__((ext_vector_type(8))) short frag8;   // 8 bf16 = 4 VGPR
typedef __attribute__((ext_vector_type(4))) float f32x4;   // MFMA acc

__device__ __forceinline__ float eluf(float v) { return v > 0.f ? v : expm1f(v); }
__device__ __forceinline__ float geluf(float v) {
  return 0.5f * v * (1.f + erff(v * 0.70710678118654752f));
}
__device__ __forceinline__ u16 f2bf(float f) {
  union { float f; unsigned int i; } v; v.f = f;
  return (u16)((v.i + 0x7fffu + ((v.i >> 16) & 1u)) >> 16);
}

#define BN_S 0.99999500003749969f   /* 1/sqrt(1+1e-5) */

// ============================================================
// k_tws1 (unchanged)
// ============================================================
__global__ void k_tws1(const float* tw1, const float* tw2, const float* tw3, const float* tw4,
                       const float* tb1, const float* tb2, const float* tb3, const float* tb4,
                       const float* bn1g, const float* bn1b,
                       float* tws1, float* c1) {
  int idx = blockIdx.x * 256 + threadIdx.x;
  if (idx < 8320) {
    int i = idx / 65, u = idx - i * 65;
    int g = i >> 5, il = i & 31;
    const float* tws[4] = {tw1, tw2, tw3, tw4};
    const int P[4] = {7, 12, 25, 32};
    int c = u - 32;
    float s1 = bn1g[i] * BN_S;
    float val = 0.f;
    int p = P[g];
    if (c >= -p && c <= p) val = s1 * tws[g][il * (2 * p + 1) + (c + p)];
    tws1[idx] = val;
  } else if (idx < 8448) {
    int i = idx - 8320;
    int g = i >> 5, il = i & 31;
    const float* tbs[4] = {tb1, tb2, tb3, tb4};
    float s1 = bn1g[i] * BN_S;
    c1[i] = s1 * tbs[g][il] + bn1b[i];
  }
}

// ============================================================
// k_weff (unchanged from r6)
// ============================================================
__global__ __launch_bounds__(256) void k_weff(const float* __restrict__ sw, const float* __restrict__ sb,
                                              const float* __restrict__ tws1, const float* __restrict__ c1,
                                              u16* __restrict__ Wb, float* __restrict__ biasEff) {
  const int lane = threadIdx.x & 63, wave = threadIdx.x >> 6;
  const int u = blockIdx.x;
  const int o = blockIdx.y * 4 + wave;
  const float* swp = sw + o * 8192 + lane;
  if (u < 65) {
    const float* tp = tws1 + u;
    float a0 = 0.f, a1 = 0.f, a2 = 0.f, a3 = 0.f;
    #pragma unroll 8
    for (int i = 0; i < 128; i += 4) {
      a0 = fmaf(swp[(i + 0) * 64], tp[(i + 0) * 65], a0);
      a1 = fmaf(swp[(i + 1) * 64], tp[(i + 1) * 65], a1);
      a2 = fmaf(swp[(i + 2) * 64], tp[(i + 2) * 65], a2);
      a3 = fmaf(swp[(i + 3) * 64], tp[(i + 3) * 65], a3);
    }
    Wb[(u * 128 + o) * 64 + lane] = f2bf((a0 + a1) + (a2 + a3));
  } else {
    float pa = 0.f;
    #pragma unroll 8
    for (int i = 0; i < 128; i++)
      pa = fmaf(swp[i * 64], c1[i], pa);
    #pragma unroll
    for (int off = 32; off; off >>= 1) pa += __shfl_xor(pa, off);
    if (lane == 0) biasEff[o] = pa + sb[o];
  }
}

// ============================================================
// k_conv (MFMA, unchanged from r4)
// ============================================================
__global__ __launch_bounds__(256) void k_conv(const float* __restrict__ x,
                                              const u16* __restrict__ Wb,
                                              const float* __restrict__ biasEff,
                                              const float* __restrict__ bn2g, const float* __restrict__ bn2b,
                                              float* __restrict__ z) {
  __shared__ u16 xs[128 * 88];
  const int tid = threadIdx.x;
  const int t0 = blockIdx.x * 64;
  const int o0 = blockIdx.y * 64;
  const int b  = blockIdx.z;

  #pragma unroll
  for (int i = 0; i < 8; i++) {
    int pos = tid + i * 256;
    int kh = pos >> 5;
    int tt = (pos & 31) * 4;
    int gt = t0 - 32 + tt;
    const float* xp = x + (b * 64 + kh) * 1000;
    float v[4];
    if (gt >= 0 && gt + 3 < 1000) {
      float4 f = *(const float4*)(xp + gt);
      v[0] = f.x; v[1] = f.y; v[2] = f.z; v[3] = f.w;
    } else {
      #pragma unroll
      for (int e = 0; e < 4; e++) { int g2 = gt + e; v[e] = (g2 >= 0 && g2 < 1000) ? xp[g2] : 0.f; }
    }
    #pragma unroll
    for (int e = 0; e < 4; e++) xs[(tt + e) * 88 + kh] = f2bf(v[e]);
  }
  __syncthreads();

  const int lane = tid & 63, wave = tid >> 6;
  const int wt = (wave & 1) * 32;
  const int wo = (wave >> 1) * 32;
  const int m = lane & 15, q = lane >> 4;

  f32x4 acc[2][2];
  #pragma unroll
  for (int i = 0; i < 2; i++)
    #pragma unroll
    for (int j = 0; j < 2; j++) acc[i][j] = (f32x4){0.f, 0.f, 0.f, 0.f};

  #pragma unroll 2
  for (int u = 0; u < 65; u++) {
    frag8 A[2][2], B[2][2];
    #pragma unroll
    for (int tp = 0; tp < 2; tp++)
      #pragma unroll
      for (int kc = 0; kc < 2; kc++)
        A[tp][kc] = *(const frag8*)&xs[(wt + tp * 16 + m + u) * 88 + kc * 32 + q * 8];
    #pragma unroll
    for (int op = 0; op < 2; op++)
      #pragma unroll
      for (int kc = 0; kc < 2; kc++)
        B[op][kc] = *(const frag8*)(Wb + ((u * 128) + o0 + wo + op * 16 + m) * 64 + kc * 32 + q * 8);
    #pragma unroll
    for (int tp = 0; tp < 2; tp++)
      #pragma unroll
      for (int op = 0; op < 2; op++) {
        acc[tp][op] = __builtin_amdgcn_mfma_f32_16x16x32_bf16(A[tp][0], B[op][0], acc[tp][op], 0, 0, 0);
        acc[tp][op] = __builtin_amdgcn_mfma_f32_16x16x32_bf16(A[tp][1], B[op][1], acc[tp][op], 0, 0, 0);
      }
  }

  #pragma unroll
  for (int op = 0; op < 2; op++) {
    int o = o0 + wo + op * 16 + m;
    float s2 = bn2g[o] * BN_S;
    float be = biasEff[o], b2 = bn2b[o];
    #pragma unroll
    for (int tp = 0; tp < 2; tp++) {
      #pragma unroll
      for (int r = 0; r < 4; r++) {
        int t = t0 + wt + tp * 16 + q * 4 + r;
        if (t < 1000)
          z[(b * 128 + o) * 1000 + t] = eluf((acc[tp][op][r] + be) * s2 + b2);
      }
    }
  }
}

// ============================================================
// k_pool (unchanged)
// ============================================================
__global__ __launch_bounds__(128) void k_pool(const float* __restrict__ z, float* __restrict__ X) {
  int p = blockIdx.x, b = blockIdx.y, o = threadIdx.x;
  const float* zp = z + (b * 128 + o) * 1000 + p * 15;
  float s = 0.f, ss = 0.f;
  #pragma unroll
  for (int k = 0; k < 50; k++) { float v = zp[k]; s += v; ss = fmaf(v, v, ss); }
  float m = s * 0.02f;
  float var = (ss - s * m) * (1.f / 49.f);
  var = fminf(fmaxf(var, 1e-6f), 1e6f);
  X[(b * 64 + p) * 128 + o] = m;
  X[((16 + b) * 64 + p) * 128 + o] = logf(var);
}

// ============================================================
// k_enc: full 4-layer transformer encoder for one bb (64 tokens, d=128).
// grid 32 blocks (bb), 256 threads (4 waves). Dynamic LDS 156672 B.
// FIX vs r8: ALL FOUR weight-staging loops were 8 iterations (64 rows) but
// Wst needs 128 rows (waves 2-3 read rows 64-127) — they multiplied against
// unwritten LDS. Now 16 iterations (4096 float4 = 128 rows x 128 cols).
// ============================================================
__global__ __launch_bounds__(256) void k_enc(
    float* __restrict__ X,
    const float* __restrict__ ln1g, const float* __restrict__ ln1b,
    const float* __restrict__ ln2g, const float* __restrict__ ln2b,
    const float* __restrict__ wq, const float* __restrict__ bq,
    const float* __restrict__ wk, const float* __restrict__ bk,
    const float* __restrict__ wv, const float* __restrict__ bv,
    const float* __restrict__ wo, const float* __restrict__ bo,
    const float* __restrict__ f1w, const float* __restrict__ f1b,
    const float* __restrict__ f2w, const float* __restrict__ f2b) {
  extern __shared__ char smem[];
  float* Xs = (float*)(smem);
  u16* Hs  = (u16*)(smem + 32768);
  u16* Wst = (u16*)(smem + 50176);
  u16* Qs  = (u16*)(smem + 84992);
  u16* Ks  = (u16*)(smem + 102400);
  u16* Vt  = (u16*)(smem + 119808);
  u16* Gd  = (u16*)(smem + 84992);
  const int tid = threadIdx.x;
  const int lane = tid & 63, w = tid >> 6;
  const int m = lane & 15, q = lane >> 4;
  u16* Ps = (u16*)(smem + (w < 2 ? 50176 + w * 9216 : 138240 + (w - 2) * 9216));
  const int bb = blockIdx.x;

  { const float4* xg = (const float4*)(X + bb * 8192);
    float4* xl = (float4*)Xs;
    for (int i = tid; i < 2048; i += 256) xl[i] = xg[i]; }

  for (int l = 0; l < 4; l++) {
    // ---------- LN1 -> Hs ----------
    __syncthreads();
    {
      const float* g = ln1g + l * 128; const float* bz = ln1b + l * 128;
      float g0 = g[lane], g1 = g[64 + lane], b0 = bz[lane], b1 = bz[64 + lane];
      for (int rr = 0; rr < 16; rr++) {
        int row = w * 16 + rr;
        float v0 = Xs[row * 128 + lane], v1 = Xs[row * 128 + 64 + lane];
        float s = v0 + v1;
        #pragma unroll
        for (int off = 32; off; off >>= 1) s += __shfl_xor(s, off);
        float mn = s * (1.f / 128.f);
        float d0 = v0 - mn, d1 = v1 - mn;
        float qs = d0 * d0 + d1 * d1;
        #pragma unroll
        for (int off = 32; off; off >>= 1) qs += __shfl_xor(qs, off);
        float rs = rsqrtf(qs * (1.f / 128.f) + 1e-5f);
        Hs[row * 136 + lane]      = f2bf(d0 * rs * g0 + b0);
        Hs[row * 136 + 64 + lane] = f2bf(d1 * rs * g1 + b1);
      }
    }
    // ---------- QKV projections ----------
    for (int p = 0; p < 3; p++) {
      const float* Wp = (p == 0 ? wq : p == 1 ? wk : wv) + l * 16384;
      const float* bp = (p == 0 ? bq : p == 1 ? bk : bv) + l * 128;
      __syncthreads();
      #pragma unroll
      for (int i = 0; i < 16; i++) {   // FIX: 128 rows
        int pos = tid + i * 256; int row = pos >> 5; int c4 = (pos & 31) * 4;
        float4 v = *(const float4*)(Wp + row * 128 + c4);
        u16* d = Wst + row * 136 + c4;
        d[0] = f2bf(v.x); d[1] = f2bf(v.y); d[2] = f2bf(v.z); d[3] = f2bf(v.w);
      }
      __syncthreads();
      f32x4 acc[4][2];
      #pragma unroll
      for (int mt = 0; mt < 4; mt++) { acc[mt][0] = (f32x4){0,0,0,0}; acc[mt][1] = (f32x4){0,0,0,0}; }
      #pragma unroll
      for (int kc = 0; kc < 4; kc++) {
        frag8 Af[4], Bf[2];
        #pragma unroll
        for (int mt = 0; mt < 4; mt++) Af[mt] = *(const frag8*)&Hs[(mt * 16 + m) * 136 + kc * 32 + q * 8];
        #pragma unroll
        for (int np = 0; np < 2; np++) Bf[np] = *(const frag8*)&Wst[(w * 32 + np * 16 + m) * 136 + kc * 32 + q * 8];
        #pragma unroll
        for (int mt = 0; mt < 4; mt++)
          #pragma unroll
          for (int np = 0; np < 2; np++)
            acc[mt][np] = __builtin_amdgcn_mfma_f32_16x16x32_bf16(Af[mt], Bf[np], acc[mt][np], 0, 0, 0);
      }
      #pragma unroll
      for (int np = 0; np < 2; np++) {
        int col = w * 32 + np * 16 + m;
        float bv2 = bp[col];
        #pragma unroll
        for (int mt = 0; mt < 4; mt++)
          #pragma unroll
          for (int r = 0; r < 4; r++) {
            int row = mt * 16 + q * 4 + r;
            float v = acc[mt][np][r] + bv2;
            if (p == 0) Qs[row * 136 + col] = f2bf(v * 0.25f);
            else if (p == 1) Ks[row * 136 + col] = f2bf(v);
            else Vt[col * 72 + row] = f2bf(v);
          }
      }
    }
    __syncthreads();
    // ---------- attention: 2 heads per wave ----------
    for (int hh = 0; hh < 2; hh++) {
      int h = w + hh * 4;
      f32x4 sc[4][4];
      #pragma unroll
      for (int mt = 0; mt < 4; mt++)
        #pragma unroll
        for (int nt = 0; nt < 4; nt++) sc[mt][nt] = (f32x4){0,0,0,0};
      frag8 Af[4], Bf[4];
      frag8 zf = {0,0,0,0,0,0,0,0};
      if (q < 2) {
        #pragma unroll
        for (int mt = 0; mt < 4; mt++) Af[mt] = *(const frag8*)&Qs[(mt * 16 + m) * 136 + h * 16 + q * 8];
        #pragma unroll
        for (int nt = 0; nt < 4; nt++) Bf[nt] = *(const frag8*)&Ks[(nt * 16 + m) * 136 + h * 16 + q * 8];
      } else {
        #pragma unroll
        for (int mt = 0; mt < 4; mt++) Af[mt] = zf;
        #pragma unroll
        for (int nt = 0; nt < 4; nt++) Bf[nt] = zf;
      }
      #pragma unroll
      for (int mt = 0; mt < 4; mt++)
        #pragma unroll
        for (int nt = 0; nt < 4; nt++)
          sc[mt][nt] = __builtin_amdgcn_mfma_f32_16x16x32_bf16(Af[mt], Bf[nt], sc[mt][nt], 0, 0, 0);
      // softmax per row + write P (normalized) to per-wave Ps in A-layout
      #pragma unroll
      for (int mt = 0; mt < 4; mt++)
        #pragma unroll
        for (int rr = 0; rr < 4; rr++) {
          float mx = fmaxf(fmaxf(sc[mt][0][rr], sc[mt][1][rr]), fmaxf(sc[mt][2][rr], sc[mt][3][rr]));
          #pragma unroll
          for (int msk = 1; msk < 16; msk <<= 1) mx = fmaxf(mx, __shfl_xor(mx, msk));
          float p0 = __expf(sc[mt][0][rr] - mx), p1 = __expf(sc[mt][1][rr] - mx);
          float p2 = __expf(sc[mt][2][rr] - mx), p3 = __expf(sc[mt][3][rr] - mx);
          float sm = (p0 + p1) + (p2 + p3);
          #pragma unroll
          for (int msk = 1; msk < 16; msk <<= 1) sm += __shfl_xor(sm, msk);
          float inv = 1.f / sm;
          int row = mt * 16 + q * 4 + rr;
          Ps[row * 72 + m]      = f2bf(p0 * inv);
          Ps[row * 72 + 16 + m] = f2bf(p1 * inv);
          Ps[row * 72 + 32 + m] = f2bf(p2 * inv);
          Ps[row * 72 + 48 + m] = f2bf(p3 * inv);
        }
      __syncthreads();   // P writes complete before PV frag reads
      // PV: M=64 N=16 K=64
      f32x4 ao[4];
      #pragma unroll
      for (int mt = 0; mt < 4; mt++) ao[mt] = (f32x4){0,0,0,0};
      #pragma unroll
      for (int kc = 0; kc < 2; kc++) {
        frag8 Vf = *(const frag8*)&Vt[(h * 16 + m) * 72 + kc * 32 + q * 8];
        #pragma unroll
        for (int mt = 0; mt < 4; mt++) {
          frag8 Pf = *(const frag8*)&Ps[(mt * 16 + m) * 72 + kc * 32 + q * 8];
          ao[mt] = __builtin_amdgcn_mfma_f32_16x16x32_bf16(Pf, Vf, ao[mt], 0, 0, 0);
        }
      }
      #pragma unroll
      for (int mt = 0; mt < 4; mt++)
        #pragma unroll
        for (int r = 0; r < 4; r++)
          Hs[(mt * 16 + q * 4 + r) * 136 + h * 16 + m] = f2bf(ao[mt][r]);
      __syncthreads();   // PV reads done before next head rewrites Ps
    }
    // ---------- O-proj + residual ----------
    __syncthreads();
    {
      const float* Wp = wo + l * 16384;
      const float* bp = bo + l * 128;
      #pragma unroll
      for (int i = 0; i < 16; i++) {   // FIX: 128 rows
        int pos = tid + i * 256; int row = pos >> 5; int c4 = (pos & 31) * 4;
        float4 v = *(const float4*)(Wp + row * 128 + c4);
        u16* d = Wst + row * 136 + c4;
        d[0] = f2bf(v.x); d[1] = f2bf(v.y); d[2] = f2bf(v.z); d[3] = f2bf(v.w);
      }
      __syncthreads();
      f32x4 acc[4][2];
      #pragma unroll
      for (int mt = 0; mt < 4; mt++) { acc[mt][0] = (f32x4){0,0,0,0}; acc[mt][1] = (f32x4){0,0,0,0}; }
      #pragma unroll
      for (int kc = 0; kc < 4; kc++) {
        frag8 Af[4], Bf[2];
        #pragma unroll
        for (int mt = 0; mt < 4; mt++) Af[mt] = *(const frag8*)&Hs[(mt * 16 + m) * 136 + kc * 32 + q * 8];
        #pragma unroll
        for (int np = 0; np < 2; np++) Bf[np] = *(const frag8*)&Wst[(w * 32 + np * 16 + m) * 136 + kc * 32 + q * 8];
        #pragma unroll
        for (int mt = 0; mt < 4; mt++)
          #pragma unroll
          for (int np = 0; np < 2; np++)
            acc[mt][np] = __builtin_amdgcn_mfma_f32_16x16x32_bf16(Af[mt], Bf[np], acc[mt][np], 0, 0, 0);
      }
      #pragma unroll
      for (int np = 0; np < 2; np++) {
        int col = w * 32 + np * 16 + m;
        float bv2 = bp[col];
        #pragma unroll
        for (int mt = 0; mt < 4; mt++)
          #pragma unroll
          for (int r = 0; r < 4; r++) {
            int row = mt * 16 + q * 4 + r;
            Xs[row * 128 + col] += acc[mt][np][r] + bv2;
          }
      }
    }
    // ---------- LN2 -> Hs ----------
    __syncthreads();
    {
      const float* g = ln2g + l * 128; const float* bz = ln2b + l * 128;
      float g0 = g[lane], g1 = g[64 + lane], b0 = bz[lane], b1 = bz[64 + lane];
      for (int rr = 0; rr < 16; rr++) {
        int row = w * 16 + rr;
        float v0 = Xs[row * 128 + lane], v1 = Xs[row * 128 + 64 + lane];
        float s = v0 + v1;
        #pragma unroll
        for (int off = 32; off; off >>= 1) s += __shfl_xor(s, off);
        float mn = s * (1.f / 128.f);
        float d0 = v0 - mn, d1 = v1 - mn;
        float qs = d0 * d0 + d1 * d1;
        #pragma unroll
        for (int off = 32; off; off >>= 1) qs += __shfl_xor(qs, off);
        float rs = rsqrtf(qs * (1.f / 128.f) + 1e-5f);
        Hs[row * 136 + lane]      = f2bf(d0 * rs * g0 + b0);
        Hs[row * 136 + 64 + lane] = f2bf(d1 * rs * g1 + b1);
      }
    }
    // ---------- F1 (+gelu) -> Gd ----------
    for (int c = 0; c < 4; c++) {
      const float* Wp = f1w + l * 65536 + c * 16384;
      __syncthreads();
      #pragma unroll
      for (int i = 0; i < 16; i++) {   // FIX: 128 rows
        int pos = tid + i * 256; int row = pos >> 5; int c4 = (pos & 31) * 4;
        float4 v = *(const float4*)(Wp + row * 128 + c4);
        u16* d = Wst + row * 136 + c4;
        d[0] = f2bf(v.x); d[1] = f2bf(v.y); d[2] = f2bf(v.z); d[3] = f2bf(v.w);
      }
      __syncthreads();
      f32x4 acc[4][2];
      #pragma unroll
      for (int mt = 0; mt < 4; mt++) { acc[mt][0] = (f32x4){0,0,0,0}; acc[mt][1] = (f32x4){0,0,0,0}; }
      #pragma unroll
      for (int kc = 0; kc < 4; kc++) {
        frag8 Af[4], Bf[2];
        #pragma unroll
        for (int mt = 0; mt < 4; mt++) Af[mt] = *(const frag8*)&Hs[(mt * 16 + m) * 136 + kc * 32 + q * 8];
        #pragma unroll
        for (int np = 0; np < 2; np++) Bf[np] = *(const frag8*)&Wst[(w * 32 + np * 16 + m) * 136 + kc * 32 + q * 8];
        #pragma unroll
        for (int mt = 0; mt < 4; mt++)
          #pragma unroll
          for (int np = 0; np < 2; np++)
            acc[mt][np] = __builtin_amdgcn_mfma_f32_16x16x32_bf16(Af[mt], Bf[np], acc[mt][np], 0, 0, 0);
      }
      const float* bp = f1b + l * 512 + c * 128;
      #pragma unroll
      for (int np = 0; np < 2; np++) {
        int col = w * 32 + np * 16 + m;
        float bv2 = bp[col];
        #pragma unroll
        for (int mt = 0; mt < 4; mt++)
          #pragma unroll
          for (int r = 0; r < 4; r++) {
            int row = mt * 16 + q * 4 + r;
            Gd[row * 520 + c * 128 + col] = f2bf(geluf(acc[mt][np][r] + bv2));
          }
      }
    }
    // ---------- F2 + residual ----------
    {
      f32x4 fa[4][2];
      #pragma unroll
      for (int mt = 0; mt < 4; mt++) { fa[mt][0] = (f32x4){0,0,0,0}; fa[mt][1] = (f32x4){0,0,0,0}; }
      for (int c = 0; c < 4; c++) {
        const float* Wp = f2w + l * 65536 + c * 128;
        __syncthreads();
        #pragma unroll
        for (int i = 0; i < 16; i++) {   // FIX: 128 rows
          int pos = tid + i * 256; int row = pos >> 5; int c4 = (pos & 31) * 4;
          float4 v = *(const float4*)(Wp + row * 512 + c4);
          u16* d = Wst + row * 136 + c4;
          d[0] = f2bf(v.x); d[1] = f2bf(v.y); d[2] = f2bf(v.z); d[3] = f2bf(v.w);
        }
        __syncthreads();
        #pragma unroll
        for (int kc = 0; kc < 4; kc++) {
          frag8 Af[4], Bf[2];
          #pragma unroll
          for (int mt = 0; mt < 4; mt++) Af[mt] = *(const frag8*)&Gd[(mt * 16 + m) * 520 + c * 128 + kc * 32 + q * 8];
          #pragma unroll
          for (int np = 0; np < 2; np++) Bf[np] = *(const frag8*)&Wst[(w * 32 + np * 16 + m) * 136 + kc * 32 + q * 8];
          #pragma unroll
          for (int mt = 0; mt < 4; mt++)
            #pragma unroll
            for (int np = 0; np < 2; np++)
              fa[mt][np] = __builtin_amdgcn_mfma_f32_16x16x32_bf16(Af[mt], Bf[np], fa[mt][np], 0, 0, 0);
        }
      }
      const float* bp = f2b + l * 128;
      #pragma unroll
      for (int np = 0; np < 2; np++) {
        int col = w * 32 + np * 16 + m;
        float bv2 = bp[col];
        #pragma unroll
        for (int mt = 0; mt < 4; mt++)
          #pragma unroll
          for (int r = 0; r < 4; r++) {
            int row = mt * 16 + q * 4 + r;
            Xs[row * 128 + col] += fa[mt][np][r] + bv2;
          }
      }
    }
  }
  __syncthreads();
  { float4* xg = (float4*)(X + bb * 8192);
    const float4* xl = (const float4*)Xs;
    for (int i = tid; i < 2048; i += 256) xg[i] = xl[i]; }
}

// ============================================================
// k_head1 / k_head2 (unchanged)
// ============================================================
__global__ __launch_bounds__(256) void k_head1(const float* __restrict__ X, const float* __restrict__ ew,
                                               const float* __restrict__ eb, const float* __restrict__ g3,
                                               const float* __restrict__ b3, float* __restrict__ G) {
  __shared__ float Xs[2][8192];
  int b = blockIdx.x, ot = blockIdx.y;
  int tid = threadIdx.x;
  {
    const float4* x1 = (const float4*)(X + b * 8192);
    const float4* x2 = (const float4*)(X + (16 + b) * 8192);
    float4* s1 = (float4*)&Xs[0][0];
    float4* s2 = (float4*)&Xs[1][0];
    for (int i = tid; i < 2048; i += 256) { s1[i] = x1[i]; s2[i] = x2[i]; }
  }
  __syncthreads();
  int w = tid & 127, og = tid >> 7;
  int oc0 = ot * 16 + og * 8;
  float a[8] = {};
  for (int ic = 0; ic < 64; ic++) {
    float x1v = Xs[0][ic * 128 + w], x2v = Xs[1][ic * 128 + w];
    #pragma unroll
    for (int j = 0; j < 8; j++) {
      a[j] = fmaf(ew[((oc0 + j) * 64 + ic) * 2 + 0], x1v, a[j]);
      a[j] = fmaf(ew[((oc0 + j) * 64 + ic) * 2 + 1], x2v, a[j]);
    }
  }
  #pragma unroll
  for (int j = 0; j < 8; j++) {
    int oc = oc0 + j;
    float v = (a[j] + eb[oc]) * (g3[oc] * BN_S) + b3[oc];
    G[(b * 64 + oc) * 128 + w] = eluf(v);
  }
}

__global__ __launch_bounds__(256) void k_head2(const float* __restrict__ G, const float* __restrict__ cw,
                                               const float* __restrict__ cb, float* __restrict__ out) {
  __shared__ float red[256];
  int b = blockIdx.x, c = blockIdx.y, tid = threadIdx.x;
  const float4* g4 = (const float4*)(G + b * 8192);
  const float4* c4 = (const float4*)(cw + c * 8192);
  float p = 0.f;
  for (int i = tid; i < 2048; i += 256) {
    float4 g = g4[i], w = c4[i];
    p += g.x * w.x + g.y * w.y + g.z * w.z + g.w * w.w;
  }
  red[tid] = p;
  __syncthreads();
  for (int s = 128; s > 0; s >>= 1) {
    if (tid < s) red[tid] += red[tid + s];
    __syncthreads();
  }
  if (tid == 0) out[b * 4 + c] = red[0] + cb[c];
}

// ============================================================
extern "C" void kernel_launch(void* const* d_in, const int* in_sizes, int n_in,
                              void* d_out, int out_size, void* d_ws, size_t ws_size,
                              hipStream_t stream) {
  const float* x    = (const float*)d_in[0];
  const float* tw1  = (const float*)d_in[1];  const float* tb1 = (const float*)d_in[2];
  const float* tw2  = (const float*)d_in[3];  const float* tb2 = (const float*)d_in[4];
  const float* tw3  = (const float*)d_in[5];  const float* tb3 = (const float*)d_in[6];
  const float* tw4  = (const float*)d_in[7];  const float* tb4 = (const float*)d_in[8];
  const float* bn1g = (const float*)d_in[9];  const float* bn1b = (const float*)d_in[10];
  const float* sw   = (const float*)d_in[11]; const float* sb   = (const float*)d_in[12];
  const float* bn2g = (const float*)d_in[13]; const float* bn2b = (const float*)d_in[14];
  const float* ln1g = (const float*)d_in[15]; const float* ln1b = (const float*)d_in[16];
  const float* ln2g = (const float*)d_in[17]; const float* ln2b = (const float*)d_in[18];
  const float* wq   = (const float*)d_in[19]; const float* bq   = (const float*)d_in[20];
  const float* wk   = (const float*)d_in[21]; const float* bk   = (const float*)d_in[22];
  const float* wv   = (const float*)d_in[23]; const float* bv   = (const float*)d_in[24];
  const float* wo   = (const float*)d_in[25]; const float* bo   = (const float*)d_in[26];
  const float* f1w  = (const float*)d_in[27]; const float* f1b  = (const float*)d_in[28];
  const float* f2w  = (const float*)d_in[29]; const float* f2b  = (const float*)d_in[30];
  const float* ew   = (const float*)d_in[31]; const float* eb   = (const float*)d_in[32];
  const float* g3   = (const float*)d_in[33]; const float* b3   = (const float*)d_in[34];
  const float* cw   = (const float*)d_in[35]; const float* cb   = (const float*)d_in[36];

  float* ws      = (float*)d_ws;
  float* tws1    = ws;               // 8320
  float* c1      = ws + 8320;        // 128
  float* biasEff = ws + 8448;        // 128
  u16*   Wb      = (u16*)(ws + 8576);// 532480 bf16 [u][o][kh]
  float* z       = ws + 541056;      // 2048000 [b][o][t]; reused as G after pool
  float* X       = ws + 2589056;     // 262144  [2048][128]
  float* G       = z;

  hipFuncSetAttribute((const void*)k_enc, hipFuncAttributeMaxDynamicSharedMemorySize, 156672);

  k_tws1<<<33, 256, 0, stream>>>(tw1, tw2, tw3, tw4, tb1, tb2, tb3, tb4, bn1g, bn1b, tws1, c1);
  k_weff<<<dim3(66, 32), 256, 0, stream>>>(sw, sb, tws1, c1, Wb, biasEff);
  k_conv<<<dim3(16, 2, 16), 256, 0, stream>>>(x, Wb, biasEff, bn2g, bn2b, z);
  k_pool<<<dim3(64, 16), 128, 0, stream>>>(z, X);

  k_enc<<<32, 256, 156672, stream>>>(X, ln1g, ln1b, ln2g, ln2b,
                                     wq, bq, wk, bk, wv, bv, wo, bo,
                                     f1w, f1b, f2w, f2b);

  k_head1<<<dim3(16, 4), 256, 0, stream>>>(X, ew, eb, g3, b3, G);
  k_head2<<<dim3(16, 4), 256, 0, stream>>>(G, cw, cb, (float*)d_out);
}